// Round 18
// baseline (44.433 us; speedup 1.0000x reference)
//
#include <hip/hip_runtime.h>
#include <hip/hip_fp16.h>

#define DIMC 64
#define KS 7
#define NTAP 49
#define GCH 8
#define NG 8
#define CMID 32
#define PADD 3
#define HH 128
#define WW 128
#define PLANE (HH*WW)
#define TW 32
#define TH 8
#define TPX (TW+2*PADD)   // 38
#define TPY (TH+2*PADD)   // 14
#define NPIX (TPX*TPY)    // 532
#define NB 4
#define WTSTR 36          // wt row stride (halves): 18 dwords, b64-aligned
#define CPAD 12

// workspace layout (bytes)
#define WC_OFF 0                                   // 8*64*64 bf16 = 65536
#define BC_OFF 65536                               // 512 f32 = 2048
#define XT_OFF 67584                               // 4*16384*64 bf16 = 8388608
#define Y16_OFF (XT_OFF + 8388608)                 // 4*8*16384*8 f16 = 8388608
#define WS_NEED ((size_t)Y16_OFF + 8388608)

typedef __attribute__((ext_vector_type(8))) short short8;
typedef __attribute__((ext_vector_type(4))) float f32x4;
typedef __fp16 fp16x2 __attribute__((ext_vector_type(2)));

static __device__ inline unsigned short f2bs(float f) {   // fp32 -> bf16 (RNE)
    union { float f; unsigned u; } v; v.f = f;
    unsigned r = v.u + 0x7fff + ((v.u >> 16) & 1);
    return (unsigned short)(r >> 16);
}

static __device__ inline unsigned pkh(float a, float b) { // 2x fp32 -> packed f16 (RTZ)
    union { fp16x2 h; unsigned u; } c;
    c.h = __builtin_amdgcn_cvt_pkrtz(a, b);
    return c.u;
}

// ---------- P: merged prep.
// blocks [0,512): xT bf16 transpose; [512,1024): y16 f16 transpose; [1024,1056): Wc/bc
__global__ __launch_bounds__(256)
void prep_all(const float* __restrict__ x, const float* __restrict__ y,
              const float* __restrict__ w1, const float* __restrict__ b1,
              const float* __restrict__ w2, const float* __restrict__ b2,
              unsigned short* __restrict__ wc, float* __restrict__ bc,
              unsigned short* __restrict__ xt, unsigned short* __restrict__ y16) {
    const int bid = blockIdx.x;
    if (bid < 1024) {
        const int bid2 = bid & 511;
        const int pxblk = bid2 & 63, rest = bid2 >> 6;
        const int b = rest & 3, h = rest >> 2;
        const int px = pxblk * 256 + threadIdx.x;
        const float* sp = ((bid < 512) ? x : y) + (size_t)b * DIMC * PLANE + (size_t)h * 32 * PLANE + px;
        unsigned short* dp = (bid < 512) ? xt : y16;
        const bool isx = (bid < 512);
        #pragma unroll
        for (int q = 0; q < 4; ++q) {
            unsigned pk[4];
            #pragma unroll
            for (int j = 0; j < 4; ++j) {
                float v0 = sp[(size_t)(q * 8 + 2 * j) * PLANE];
                float v1 = sp[(size_t)(q * 8 + 2 * j + 1) * PLANE];
                pk[j] = isx ? (((unsigned)f2bs(v1) << 16) | f2bs(v0)) : pkh(v0, v1);
            }
            *reinterpret_cast<uint4*>(dp + (((size_t)b * 8 + h * 4 + q) * PLANE + px) * 8) =
                make_uint4(pk[0], pk[1], pk[2], pk[3]);
        }
    } else {
        const int idx = (bid - 1024) * 256 + threadIdx.x;   // 0..8191
        const int row64 = idx >> 4;                         // 0..511
        const int c0 = (idx & 15) * 4;
        const int g = row64 >> 6, r = row64 & 63;
        float a0 = 0.f, a1 = 0.f, a2 = 0.f, a3 = 0.f, bv = 0.f;
        if (r < NTAP) {
            const float* w2r = w2 + (g * NTAP + r) * CMID;
            #pragma unroll
            for (int m = 0; m < CMID; ++m) {
                float wv = w2r[m];
                const float* w1r = w1 + m * DIMC + c0;
                a0 = fmaf(wv, w1r[0], a0);
                a1 = fmaf(wv, w1r[1], a1);
                a2 = fmaf(wv, w1r[2], a2);
                a3 = fmaf(wv, w1r[3], a3);
            }
            if (c0 == 0) {
                bv = b2[g * NTAP + r];
                #pragma unroll
                for (int m = 0; m < CMID; ++m) bv = fmaf(w2r[m], b1[m], bv);
            }
        }
        *reinterpret_cast<uint2*>(wc + row64 * DIMC + c0) =
            make_uint2(((unsigned)f2bs(a1) << 16) | f2bs(a0),
                       ((unsigned)f2bs(a3) << 16) | f2bs(a2));
        if ((idx & 15) == 0) bc[row64] = bv;
    }
}

// ---------- Kernel B: 2 groups per block — bf (xt) fragments and block fixed
// costs shared; af for group 1 loaded under involution 0 (acc0 dead there). ----------
__global__ __launch_bounds__(256, 4)
void invol_mfma12_kernel(const unsigned short* __restrict__ y16,
                         const unsigned short* __restrict__ xt,
                         const unsigned short* __restrict__ wc,
                         const float* __restrict__ bc,
                         float* __restrict__ out) {
    __shared__ __half ytile[2][NPIX * GCH];   // 17024 B
    __shared__ __half wtl[256 * WTSTR];       // 18432 B (wave-private, reused per group)

    const int tid = threadIdx.x;
    const int l = tid & 63, w = tid >> 6;
    const int fr = l & 15, fk = l >> 4;
    const int bx = blockIdx.x, by = blockIdx.y;
    const int b = blockIdx.z >> 2, g0 = (blockIdx.z & 3) * 2;
    const int tx = tid & 31, ty = tid >> 5;

    // ---- (1) hoisted global loads: bf (xt, group-independent), af group 0 ----
    int gpix[4];
    #pragma unroll
    for (int nt = 0; nt < 4; ++nt) {
        int lp = w * 64 + nt * 16 + fr;
        gpix[nt] = (by * TH + (lp >> 5)) * WW + bx * TW + (lp & 31);
    }
    short8 bf[2][4];
    #pragma unroll
    for (int kp = 0; kp < 2; ++kp)
        #pragma unroll
        for (int nt = 0; nt < 4; ++nt) {
            union { uint4 u; short8 s; } cv;
            cv.u = *reinterpret_cast<const uint4*>(
                xt + (((size_t)b * 8 + kp * 4 + fk) * PLANE + gpix[nt]) * 8);
            bf[kp][nt] = cv.s;
        }
    short8 af[2][4][2];                       // [group][m-tile][kp]; af[1] loaded late
    #pragma unroll
    for (int dmt = 0; dmt < 4; ++dmt)
        #pragma unroll
        for (int kp = 0; kp < 2; ++kp) {
            union { uint4 u; short8 s; } cv;
            cv.u = *reinterpret_cast<const uint4*>(
                wc + ((size_t)(g0 * 64 + dmt * 16 + fr)) * DIMC + kp * 32 + fk * 8);
            af[0][dmt][kp] = cv.s;
        }

    // ---- (2) stage y halo for BOTH groups: 1 b128 load + ds_write per (group,pixel) ----
    #pragma unroll
    for (int k = 0; k < 5; ++k) {
        int i = tid + k * 256;
        if (i < NPIX * 2) {
            int gg = i / NPIX;
            int px = i - gg * NPIX;
            int r = px / TPX, col = px - r * TPX;
            int sy = by * TH + r - PADD, sx = bx * TW + col - PADD;
            bool ok = (sy >= 0 && sy < HH && sx >= 0 && sx < WW);
            uint4 v = make_uint4(0u, 0u, 0u, 0u);
            if (ok) v = *reinterpret_cast<const uint4*>(
                y16 + (((size_t)(b * 8 + g0 + gg) * PLANE) + (size_t)(sy * WW + sx)) * 8);
            *reinterpret_cast<uint4*>(&ytile[gg][px * GCH]) = v;
        }
    }

    __syncthreads();   // ytile visible; all VMEM in flight/landed

    const int ybase = (ty * TPX + tx) * GCH;
    const int gy = by * TH + ty, gx = bx * TW + tx;

    #pragma unroll
    for (int gg = 0; gg < 2; ++gg) {
        const int g = g0 + gg;

        // GEMM both chunks sequentially (R13 pattern), wtl per chunk
        __half2 acch[4];
        #pragma unroll
        for (int cc = 0; cc < 4; ++cc) acch[cc] = __float2half2_rn(0.f);

        #pragma unroll
        for (int mc = 0; mc < 2; ++mc) {
            f32x4 acc[2][4];
            #pragma unroll
            for (int dm = 0; dm < 2; ++dm)
                #pragma unroll
                for (int nt = 0; nt < 4; ++nt)
                    acc[dm][nt] = f32x4{0.f, 0.f, 0.f, 0.f};

            #pragma unroll
            for (int dm = 0; dm < 2; ++dm)
                #pragma unroll
                for (int kp = 0; kp < 2; ++kp)
                    #pragma unroll
                    for (int nt = 0; nt < 4; ++nt)
                        acc[dm][nt] = __builtin_amdgcn_mfma_f32_16x16x32_bf16(
                            af[gg][mc * 2 + dm][kp], bf[kp][nt], acc[dm][nt], 0, 0, 0);

            #pragma unroll
            for (int dm = 0; dm < 2; ++dm) {
                int rb = (mc * 2 + dm) * 16 + fk * 4;
                float4 bb = *reinterpret_cast<const float4*>(&bc[g * 64 + rb]);
                #pragma unroll
                for (int nt = 0; nt < 4; ++nt) {
                    int lp = w * 64 + nt * 16 + fr;
                    *reinterpret_cast<uint2*>(&wtl[lp * WTSTR + dm * 16 + fk * 4]) =
                        make_uint2(pkh(acc[dm][nt][0] + bb.x, acc[dm][nt][1] + bb.y),
                                   pkh(acc[dm][nt][2] + bb.z, acc[dm][nt][3] + bb.w));
                }
            }

            // group-1 af loads issued once, after chunk-0 write (acc dead, hides
            // under the upcoming involution; NOT immediately consumed — R11 lesson)
            if (gg == 0 && mc == 0) {
                #pragma unroll
                for (int dmt = 0; dmt < 4; ++dmt)
                    #pragma unroll
                    for (int kp = 0; kp < 2; ++kp) {
                        union { uint4 u; short8 s; } cv;
                        cv.u = *reinterpret_cast<const uint4*>(
                            wc + ((size_t)((g0 + 1) * 64 + dmt * 16 + fr)) * DIMC + kp * 32 + fk * 8);
                        af[1][dmt][kp] = cv.s;
                    }
            }

            uint2 wr[8];
            #pragma unroll
            for (int q = 0; q < 8; ++q)
                wr[q] = *reinterpret_cast<const uint2*>(&wtl[tid * WTSTR + q * 4]);

            const int ninv = (mc == 0) ? 32 : 17;          // kk 0..31 / 32..48
            #pragma unroll
            for (int j = 0; j < 32; ++j) {
                if (j >= ninv) break;
                const int kk = mc * 32 + j;
                const int ky = kk / 7, kx = kk - ky * 7;
                unsigned uh = (j & 2) ? wr[j >> 2].y : wr[j >> 2].x;
                union { unsigned u; __half2 h; } hc; hc.u = uh;
                __half wh = (j & 1) ? __high2half(hc.h) : __low2half(hc.h);
                __half2 wv2 = __half2half2(wh);
                union { uint4 u; __half2 h[4]; } yvv;
                yvv.u = *reinterpret_cast<const uint4*>(&ytile[gg][ybase + (ky * TPX + kx) * GCH]);
                acch[0] = __hfma2(wv2, yvv.h[0], acch[0]);
                acch[1] = __hfma2(wv2, yvv.h[1], acch[1]);
                acch[2] = __hfma2(wv2, yvv.h[2], acch[2]);
                acch[3] = __hfma2(wv2, yvv.h[3], acch[3]);
            }
        }

        float* op = out + ((size_t)(b * DIMC + g * GCH) * HH + gy) * WW + gx;
        #pragma unroll
        for (int cc = 0; cc < 4; ++cc) {
            float2 f = __half22float2(acch[cc]);
            op[(2 * cc) * PLANE]     = f.x;
            op[(2 * cc + 1) * PLANE] = f.y;
        }
    }
}

// ---------- Fallback (known-good R2 fused kernel) ----------
__global__ __launch_bounds__(256, 1)
void invol_fused_kernel(const float* __restrict__ x, const float* __restrict__ y,
                        const float* __restrict__ w1, const float* __restrict__ b1,
                        const float* __restrict__ w2, const float* __restrict__ b2,
                        float* __restrict__ out) {
    __shared__ float ytile[NPIX * CPAD];
    const int tid = threadIdx.x;
    const int tx = tid & 31, ty = tid >> 5;
    const int bx = blockIdx.x, by = blockIdx.y, bz = blockIdx.z;
    const int gx = bx * TW + tx, gy = by * TH + ty;

    float xv[DIMC];
    const float* xp = x + ((size_t)(bz * DIMC) * HH + gy) * WW + gx;
    #pragma unroll
    for (int c = 0; c < DIMC; ++c) xv[c] = xp[c * PLANE];

    float mid[CMID];
    #pragma unroll
    for (int m = 0; m < CMID; ++m) {
        float a = b1[m];
        const float4* w1r = reinterpret_cast<const float4*>(w1 + m * DIMC);
        #pragma unroll
        for (int cq = 0; cq < DIMC / 4; ++cq) {
            float4 wv = w1r[cq];
            a = fmaf(wv.x, xv[4*cq+0], a);
            a = fmaf(wv.y, xv[4*cq+1], a);
            a = fmaf(wv.z, xv[4*cq+2], a);
            a = fmaf(wv.w, xv[4*cq+3], a);
        }
        mid[m] = a;
    }

    for (int g = 0; g < NG; ++g) {
        __syncthreads();
        for (int i = tid; i < NPIX * GCH; i += 256) {
            int c = i / NPIX;
            int p = i - c * NPIX;
            int r = p / TPX;
            int col = p - r * TPX;
            int sy = by * TH + r - PADD;
            int sx = bx * TW + col - PADD;
            float v = 0.f;
            if (sy >= 0 && sy < HH && sx >= 0 && sx < WW)
                v = y[((size_t)(bz * DIMC + g * GCH + c) * HH + sy) * WW + sx];
            ytile[p * CPAD + c] = v;
        }
        __syncthreads();

        float wt[NTAP];
        const float*  b2g = b2 + g * NTAP;
        const float4* w2g = reinterpret_cast<const float4*>(w2 + g * NTAP * CMID);
        #pragma unroll
        for (int kk = 0; kk < NTAP; ++kk) {
            float a = b2g[kk];
            #pragma unroll
            for (int mq = 0; mq < CMID / 4; ++mq) {
                float4 wv = w2g[kk * (CMID / 4) + mq];
                a = fmaf(wv.x, mid[4*mq+0], a);
                a = fmaf(wv.y, mid[4*mq+1], a);
                a = fmaf(wv.z, mid[4*mq+2], a);
                a = fmaf(wv.w, mid[4*mq+3], a);
            }
            wt[kk] = a;
        }

        float acc[GCH];
        #pragma unroll
        for (int cc = 0; cc < GCH; ++cc) acc[cc] = 0.f;
        #pragma unroll
        for (int ky = 0; ky < KS; ++ky) {
            #pragma unroll
            for (int kx = 0; kx < KS; ++kx) {
                float wv = wt[ky * KS + kx];
                int pp = (ty + ky) * TPX + (tx + kx);
                const float4* yr = reinterpret_cast<const float4*>(&ytile[pp * CPAD]);
                float4 ya = yr[0];
                float4 yb = yr[1];
                acc[0] = fmaf(wv, ya.x, acc[0]);
                acc[1] = fmaf(wv, ya.y, acc[1]);
                acc[2] = fmaf(wv, ya.z, acc[2]);
                acc[3] = fmaf(wv, ya.w, acc[3]);
                acc[4] = fmaf(wv, yb.x, acc[4]);
                acc[5] = fmaf(wv, yb.y, acc[5]);
                acc[6] = fmaf(wv, yb.z, acc[6]);
                acc[7] = fmaf(wv, yb.w, acc[7]);
            }
        }

        float* op = out + ((size_t)(bz * DIMC + g * GCH) * HH + gy) * WW + gx;
        #pragma unroll
        for (int cc = 0; cc < GCH; ++cc) op[cc * PLANE] = acc[cc];
    }
}

extern "C" void kernel_launch(void* const* d_in, const int* in_sizes, int n_in,
                              void* d_out, int out_size, void* d_ws, size_t ws_size,
                              hipStream_t stream) {
    const float* x  = (const float*)d_in[0];
    const float* y  = (const float*)d_in[1];
    const float* w1 = (const float*)d_in[2];
    const float* b1 = (const float*)d_in[3];
    const float* w2 = (const float*)d_in[4];
    const float* b2 = (const float*)d_in[5];
    float* out = (float*)d_out;

    if (ws_size >= WS_NEED) {
        char* ws = (char*)d_ws;
        unsigned short* wcp  = (unsigned short*)(ws + WC_OFF);
        float*          bcp  = (float*)(ws + BC_OFF);
        unsigned short* xtp  = (unsigned short*)(ws + XT_OFF);
        unsigned short* y16p = (unsigned short*)(ws + Y16_OFF);

        hipLaunchKernelGGL(prep_all, dim3(1024 + 32), dim3(256), 0, stream,
                           x, y, w1, b1, w2, b2, wcp, bcp, xtp, y16p);
        hipLaunchKernelGGL(invol_mfma12_kernel, dim3(WW / TW, HH / TH, NB * NG / 2), dim3(256), 0, stream,
                           y16p, xtp, wcp, bcp, out);
    } else {
        dim3 grid(WW / TW, HH / TH, NB);
        hipLaunchKernelGGL(invol_fused_kernel, grid, dim3(256), 0, stream,
                           x, y, w1, b1, w2, b2, out);
    }
}

// Round 19
// 34.179 us; speedup vs baseline: 1.3000x; 1.3000x over previous
//
#include <hip/hip_runtime.h>
#include <hip/hip_fp16.h>

#define DIMC 64
#define KS 7
#define NTAP 49
#define GCH 8
#define NG 8
#define CMID 32
#define PADD 3
#define HH 128
#define WW 128
#define PLANE (HH*WW)
#define TW 32
#define TH 8
#define TPX (TW+2*PADD)   // 38
#define TPY (TH+2*PADD)   // 14
#define NPIX (TPX*TPY)    // 532
#define NB 4
#define WTSTR 36          // wt row stride (halves): 18 dwords, b64-aligned
#define CPAD 12

// workspace layout (bytes)
#define WC_OFF 0                                   // 8*64*64 bf16 = 65536
#define BC_OFF 65536                               // 512 f32 = 2048
#define XT_OFF 67584                               // 4*16384*64 bf16 = 8388608
#define Y16_OFF (XT_OFF + 8388608)                 // 4*8*16384*8 f16 = 8388608
#define WS_NEED ((size_t)Y16_OFF + 8388608)

typedef __attribute__((ext_vector_type(8))) short short8;
typedef __attribute__((ext_vector_type(4))) float f32x4;
typedef __fp16 fp16x2 __attribute__((ext_vector_type(2)));

static __device__ inline unsigned short f2bs(float f) {   // fp32 -> bf16 (RNE)
    union { float f; unsigned u; } v; v.f = f;
    unsigned r = v.u + 0x7fff + ((v.u >> 16) & 1);
    return (unsigned short)(r >> 16);
}

static __device__ inline unsigned pkh(float a, float b) { // 2x fp32 -> packed f16 (RTZ)
    union { fp16x2 h; unsigned u; } c;
    c.h = __builtin_amdgcn_cvt_pkrtz(a, b);
    return c.u;
}

// ---------- P: merged prep.
// blocks [0,512): xT bf16 transpose; [512,1024): y16 f16 transpose; [1024,1056): Wc/bc
__global__ __launch_bounds__(256)
void prep_all(const float* __restrict__ x, const float* __restrict__ y,
              const float* __restrict__ w1, const float* __restrict__ b1,
              const float* __restrict__ w2, const float* __restrict__ b2,
              unsigned short* __restrict__ wc, float* __restrict__ bc,
              unsigned short* __restrict__ xt, unsigned short* __restrict__ y16) {
    const int bid = blockIdx.x;
    if (bid < 1024) {
        const int bid2 = bid & 511;
        const int pxblk = bid2 & 63, rest = bid2 >> 6;
        const int b = rest & 3, h = rest >> 2;
        const int px = pxblk * 256 + threadIdx.x;
        const float* sp = ((bid < 512) ? x : y) + (size_t)b * DIMC * PLANE + (size_t)h * 32 * PLANE + px;
        unsigned short* dp = (bid < 512) ? xt : y16;
        const bool isx = (bid < 512);
        #pragma unroll
        for (int q = 0; q < 4; ++q) {
            unsigned pk[4];
            #pragma unroll
            for (int j = 0; j < 4; ++j) {
                float v0 = sp[(size_t)(q * 8 + 2 * j) * PLANE];
                float v1 = sp[(size_t)(q * 8 + 2 * j + 1) * PLANE];
                pk[j] = isx ? (((unsigned)f2bs(v1) << 16) | f2bs(v0)) : pkh(v0, v1);
            }
            *reinterpret_cast<uint4*>(dp + (((size_t)b * 8 + h * 4 + q) * PLANE + px) * 8) =
                make_uint4(pk[0], pk[1], pk[2], pk[3]);
        }
    } else {
        const int idx = (bid - 1024) * 256 + threadIdx.x;   // 0..8191
        const int row64 = idx >> 4;                         // 0..511
        const int c0 = (idx & 15) * 4;
        const int g = row64 >> 6, r = row64 & 63;
        float a0 = 0.f, a1 = 0.f, a2 = 0.f, a3 = 0.f, bv = 0.f;
        if (r < NTAP) {
            const float* w2r = w2 + (g * NTAP + r) * CMID;
            #pragma unroll
            for (int m = 0; m < CMID; ++m) {
                float wv = w2r[m];
                const float* w1r = w1 + m * DIMC + c0;
                a0 = fmaf(wv, w1r[0], a0);
                a1 = fmaf(wv, w1r[1], a1);
                a2 = fmaf(wv, w1r[2], a2);
                a3 = fmaf(wv, w1r[3], a3);
            }
            if (c0 == 0) {
                bv = b2[g * NTAP + r];
                #pragma unroll
                for (int m = 0; m < CMID; ++m) bv = fmaf(w2r[m], b1[m], bv);
            }
        }
        *reinterpret_cast<uint2*>(wc + row64 * DIMC + c0) =
            make_uint2(((unsigned)f2bs(a1) << 16) | f2bs(a0),
                       ((unsigned)f2bs(a3) << 16) | f2bs(a2));
        if ((idx & 15) == 0) bc[row64] = bv;
    }
}

// ---------- Kernel B (R13 best): all global loads hoisted upfront; post-barrier
// path is pure reg-MFMA -> wave-private wtl -> involution (no VMEM waits). ----------
__global__ __launch_bounds__(256, 4)
void invol_mfma8_kernel(const unsigned short* __restrict__ y16,
                        const unsigned short* __restrict__ xt,
                        const unsigned short* __restrict__ wc,
                        const float* __restrict__ bc,
                        float* __restrict__ out) {
    __shared__ __half ytile[NPIX * GCH];     // 8512 B
    __shared__ __half wtl[256 * WTSTR];      // 18432 B (wave-private 64-row slices)

    const int tid = threadIdx.x;
    const int l = tid & 63, w = tid >> 6;
    const int fr = l & 15, fk = l >> 4;
    const int bx = blockIdx.x, by = blockIdx.y;
    const int b = blockIdx.z >> 3, g = blockIdx.z & 7;
    const int tx = tid & 31, ty = tid >> 5;

    // ---- (1) ALL global loads upfront: bf (xt), af (wc) ----
    int gpix[4];
    #pragma unroll
    for (int nt = 0; nt < 4; ++nt) {
        int lp = w * 64 + nt * 16 + fr;
        gpix[nt] = (by * TH + (lp >> 5)) * WW + bx * TW + (lp & 31);
    }
    short8 bf[2][4];
    #pragma unroll
    for (int kp = 0; kp < 2; ++kp)
        #pragma unroll
        for (int nt = 0; nt < 4; ++nt) {
            union { uint4 u; short8 s; } cv;
            cv.u = *reinterpret_cast<const uint4*>(
                xt + (((size_t)b * 8 + kp * 4 + fk) * PLANE + gpix[nt]) * 8);
            bf[kp][nt] = cv.s;
        }
    short8 af[4][2];                          // [m-tile][kp]
    #pragma unroll
    for (int dmt = 0; dmt < 4; ++dmt)
        #pragma unroll
        for (int kp = 0; kp < 2; ++kp) {
            union { uint4 u; short8 s; } cv;
            cv.u = *reinterpret_cast<const uint4*>(
                wc + ((size_t)(g * 64 + dmt * 16 + fr)) * DIMC + kp * 32 + fk * 8);
            af[dmt][kp] = cv.s;
        }

    // ---- (2) stage y halo: 1 b128 load + 1 b128 ds_write per pixel ----
    const unsigned short* y16g = y16 + ((size_t)(b * 8 + g) * PLANE) * 8;
    #pragma unroll
    for (int k = 0; k < 3; ++k) {
        int i = tid + k * 256;
        if (i < NPIX) {
            int r = i / TPX, col = i - r * TPX;
            int sy = by * TH + r - PADD, sx = bx * TW + col - PADD;
            bool ok = (sy >= 0 && sy < HH && sx >= 0 && sx < WW);
            uint4 v = make_uint4(0u, 0u, 0u, 0u);
            if (ok) v = *reinterpret_cast<const uint4*>(y16g + (size_t)(sy * WW + sx) * 8);
            *reinterpret_cast<uint4*>(&ytile[i * GCH]) = v;
        }
    }

    __syncthreads();   // ytile visible; all VMEM already in flight/landed

    // ---- (3) two super-chunks, barrier-free (wtl is wave-private) ----
    __half2 acch[4];
    #pragma unroll
    for (int cc = 0; cc < 4; ++cc) acch[cc] = __float2half2_rn(0.f);
    const int ybase = (ty * TPX + tx) * GCH;

    #pragma unroll
    for (int mc = 0; mc < 2; ++mc) {
        f32x4 acc[2][4];
        #pragma unroll
        for (int dm = 0; dm < 2; ++dm)
            #pragma unroll
            for (int nt = 0; nt < 4; ++nt)
                acc[dm][nt] = f32x4{0.f, 0.f, 0.f, 0.f};

        #pragma unroll
        for (int dm = 0; dm < 2; ++dm)
            #pragma unroll
            for (int kp = 0; kp < 2; ++kp)
                #pragma unroll
                for (int nt = 0; nt < 4; ++nt)
                    acc[dm][nt] = __builtin_amdgcn_mfma_f32_16x16x32_bf16(
                        af[mc * 2 + dm][kp], bf[kp][nt], acc[dm][nt], 0, 0, 0);

        // bias + write super-chunk into this wave's private wtl rows
        #pragma unroll
        for (int dm = 0; dm < 2; ++dm) {
            int rb = (mc * 2 + dm) * 16 + fk * 4;
            float4 bb = *reinterpret_cast<const float4*>(&bc[g * 64 + rb]);
            #pragma unroll
            for (int nt = 0; nt < 4; ++nt) {
                int lp = w * 64 + nt * 16 + fr;
                *reinterpret_cast<uint2*>(&wtl[lp * WTSTR + dm * 16 + fk * 4]) =
                    make_uint2(pkh(acc[dm][nt][0] + bb.x, acc[dm][nt][1] + bb.y),
                               pkh(acc[dm][nt][2] + bb.z, acc[dm][nt][3] + bb.w));
            }
        }

        // read own 32 taps back (same wave wrote them; lgkmcnt orders it)
        uint2 wr[8];
        #pragma unroll
        for (int q = 0; q < 8; ++q)
            wr[q] = *reinterpret_cast<const uint2*>(&wtl[tid * WTSTR + q * 4]);

        const int ninv = (mc == 0) ? 32 : 17;          // kk 0..31 / 32..48
        #pragma unroll
        for (int j = 0; j < 32; ++j) {
            if (j >= ninv) break;
            const int kk = mc * 32 + j;
            const int ky = kk / 7, kx = kk - ky * 7;
            unsigned uh = (j & 2) ? wr[j >> 2].y : wr[j >> 2].x;
            union { unsigned u; __half2 h; } hc; hc.u = uh;
            __half wh = (j & 1) ? __high2half(hc.h) : __low2half(hc.h);
            __half2 wv2 = __half2half2(wh);
            union { uint4 u; __half2 h[4]; } yvv;
            yvv.u = *reinterpret_cast<const uint4*>(&ytile[ybase + (ky * TPX + kx) * GCH]);
            acch[0] = __hfma2(wv2, yvv.h[0], acch[0]);
            acch[1] = __hfma2(wv2, yvv.h[1], acch[1]);
            acch[2] = __hfma2(wv2, yvv.h[2], acch[2]);
            acch[3] = __hfma2(wv2, yvv.h[3], acch[3]);
        }
    }

    const int gy = by * TH + ty, gx = bx * TW + tx;
    float* op = out + ((size_t)(b * DIMC + g * GCH) * HH + gy) * WW + gx;
    #pragma unroll
    for (int cc = 0; cc < 4; ++cc) {
        float2 f = __half22float2(acch[cc]);
        op[(2 * cc) * PLANE]     = f.x;
        op[(2 * cc + 1) * PLANE] = f.y;
    }
}

// ---------- Fallback (known-good R2 fused kernel) ----------
__global__ __launch_bounds__(256, 1)
void invol_fused_kernel(const float* __restrict__ x, const float* __restrict__ y,
                        const float* __restrict__ w1, const float* __restrict__ b1,
                        const float* __restrict__ w2, const float* __restrict__ b2,
                        float* __restrict__ out) {
    __shared__ float ytile[NPIX * CPAD];
    const int tid = threadIdx.x;
    const int tx = tid & 31, ty = tid >> 5;
    const int bx = blockIdx.x, by = blockIdx.y, bz = blockIdx.z;
    const int gx = bx * TW + tx, gy = by * TH + ty;

    float xv[DIMC];
    const float* xp = x + ((size_t)(bz * DIMC) * HH + gy) * WW + gx;
    #pragma unroll
    for (int c = 0; c < DIMC; ++c) xv[c] = xp[c * PLANE];

    float mid[CMID];
    #pragma unroll
    for (int m = 0; m < CMID; ++m) {
        float a = b1[m];
        const float4* w1r = reinterpret_cast<const float4*>(w1 + m * DIMC);
        #pragma unroll
        for (int cq = 0; cq < DIMC / 4; ++cq) {
            float4 wv = w1r[cq];
            a = fmaf(wv.x, xv[4*cq+0], a);
            a = fmaf(wv.y, xv[4*cq+1], a);
            a = fmaf(wv.z, xv[4*cq+2], a);
            a = fmaf(wv.w, xv[4*cq+3], a);
        }
        mid[m] = a;
    }

    for (int g = 0; g < NG; ++g) {
        __syncthreads();
        for (int i = tid; i < NPIX * GCH; i += 256) {
            int c = i / NPIX;
            int p = i - c * NPIX;
            int r = p / TPX;
            int col = p - r * TPX;
            int sy = by * TH + r - PADD;
            int sx = bx * TW + col - PADD;
            float v = 0.f;
            if (sy >= 0 && sy < HH && sx >= 0 && sx < WW)
                v = y[((size_t)(bz * DIMC + g * GCH + c) * HH + sy) * WW + sx];
            ytile[p * CPAD + c] = v;
        }
        __syncthreads();

        float wt[NTAP];
        const float*  b2g = b2 + g * NTAP;
        const float4* w2g = reinterpret_cast<const float4*>(w2 + g * NTAP * CMID);
        #pragma unroll
        for (int kk = 0; kk < NTAP; ++kk) {
            float a = b2g[kk];
            #pragma unroll
            for (int mq = 0; mq < CMID / 4; ++mq) {
                float4 wv = w2g[kk * (CMID / 4) + mq];
                a = fmaf(wv.x, mid[4*mq+0], a);
                a = fmaf(wv.y, mid[4*mq+1], a);
                a = fmaf(wv.z, mid[4*mq+2], a);
                a = fmaf(wv.w, mid[4*mq+3], a);
            }
            wt[kk] = a;
        }

        float acc[GCH];
        #pragma unroll
        for (int cc = 0; cc < GCH; ++cc) acc[cc] = 0.f;
        #pragma unroll
        for (int ky = 0; ky < KS; ++ky) {
            #pragma unroll
            for (int kx = 0; kx < KS; ++kx) {
                float wv = wt[ky * KS + kx];
                int pp = (ty + ky) * TPX + (tx + kx);
                const float4* yr = reinterpret_cast<const float4*>(&ytile[pp * CPAD]);
                float4 ya = yr[0];
                float4 yb = yr[1];
                acc[0] = fmaf(wv, ya.x, acc[0]);
                acc[1] = fmaf(wv, ya.y, acc[1]);
                acc[2] = fmaf(wv, ya.z, acc[2]);
                acc[3] = fmaf(wv, ya.w, acc[3]);
                acc[4] = fmaf(wv, yb.x, acc[4]);
                acc[5] = fmaf(wv, yb.y, acc[5]);
                acc[6] = fmaf(wv, yb.z, acc[6]);
                acc[7] = fmaf(wv, yb.w, acc[7]);
            }
        }

        float* op = out + ((size_t)(bz * DIMC + g * GCH) * HH + gy) * WW + gx;
        #pragma unroll
        for (int cc = 0; cc < GCH; ++cc) op[cc * PLANE] = acc[cc];
    }
}

extern "C" void kernel_launch(void* const* d_in, const int* in_sizes, int n_in,
                              void* d_out, int out_size, void* d_ws, size_t ws_size,
                              hipStream_t stream) {
    const float* x  = (const float*)d_in[0];
    const float* y  = (const float*)d_in[1];
    const float* w1 = (const float*)d_in[2];
    const float* b1 = (const float*)d_in[3];
    const float* w2 = (const float*)d_in[4];
    const float* b2 = (const float*)d_in[5];
    float* out = (float*)d_out;

    if (ws_size >= WS_NEED) {
        char* ws = (char*)d_ws;
        unsigned short* wcp  = (unsigned short*)(ws + WC_OFF);
        float*          bcp  = (float*)(ws + BC_OFF);
        unsigned short* xtp  = (unsigned short*)(ws + XT_OFF);
        unsigned short* y16p = (unsigned short*)(ws + Y16_OFF);

        hipLaunchKernelGGL(prep_all, dim3(1024 + 32), dim3(256), 0, stream,
                           x, y, w1, b1, w2, b2, wcp, bcp, xtp, y16p);
        hipLaunchKernelGGL(invol_mfma8_kernel, dim3(WW / TW, HH / TH, NB * NG), dim3(256), 0, stream,
                           y16p, xtp, wcp, bcp, out);
    } else {
        dim3 grid(WW / TW, HH / TH, NB);
        hipLaunchKernelGGL(invol_fused_kernel, grid, dim3(256), 0, stream,
                           x, y, w1, b1, w2, b2, out);
    }
}